// Round 21
// baseline (132.992 us; speedup 1.0000x reference)
//
#include <hip/hip_runtime.h>

// PTConv fused: out[i] = (sum_{e: dst=i} relu([x_src, pos_s-pos_i] @ W1 + b1)) @ W2 + deg(i)*b2
// Pipeline: phase-A hist(transposed, EPBA=2048)->parallel scan(64 blocks)->place
// (claim-free) into 49 super-buckets; phase-B claim-based re-scatter into 16-node
// fine buckets; k_main: LDS counting-sort + cvt_pk features + effective-bias
// packed-f32 relu-MLP, then FUSED MFMA @W2 epilogue (acc->LDS A-frags, B from
// L2-hot pre-converted bf16 W2^T, out written directly). No separate k_w2.

#define HIDDEN 128
#define BNODES 16       // nodes per fine bucket
#define BSH 4           // log2(BNODES)
#define SUPSH 10        // super bucket = dst >> 10 (1024 nodes = 64 fine buckets)
#define CAPA 36864      // slots per super bucket (avg 32.7K; +23 sigma)
#define CAPF 768        // slots per fine bucket (avg 512; +11 sigma)
#define EPBA 2048       // edges per phase-A block
#define KSUB 16         // phase-B blocks per super bucket
#define SThrB 512
#define ALDS 132        // accLds row stride (floats): 528B, 16B-aligned, 2-way banks

typedef float v2f __attribute__((ext_vector_type(2)));
typedef short bf16x8 __attribute__((ext_vector_type(8)));
typedef float f32x4 __attribute__((ext_vector_type(4)));

__device__ __forceinline__ unsigned cvt_pk_bf16(float lo, float hi) {
    unsigned r;
    asm("v_cvt_pk_bf16_f32 %0, %1, %2" : "=v"(r) : "v"(lo), "v"(hi));
    return r;   // [15:0]=bf16(lo), [31:16]=bf16(hi)
}

__device__ __forceinline__ unsigned short f2bf(float f) {
    unsigned int u = __float_as_uint(f);
    u += 0x7fffu + ((u >> 16) & 1u);   // round-to-nearest-even
    return (unsigned short)(u >> 16);
}

// Phase A1: per-block 64-bin histogram, written TRANSPOSED: histA[s*NBLK + b].
// Also packs xpos[n] = {x, px, py, 0}; last block converts W2 -> transposed bf16.
__global__ __launch_bounds__(256) void k_histA(const int* __restrict__ dst,
                                               const float* __restrict__ x,
                                               const float* __restrict__ pos,
                                               const float* __restrict__ W2,
                                               int* __restrict__ histA,
                                               float4* __restrict__ xpos,
                                               unsigned short* __restrict__ w2bfT,
                                               int E, int N, int NBLK) {
    __shared__ int h[64];
    int tid = threadIdx.x;
    if (tid < 64) h[tid] = 0;
    int nb = blockIdx.x * 64 + tid;
    if (tid < 64 && nb < N) {
        float2 p = ((const float2*)pos)[nb];
        xpos[nb] = make_float4(x[nb], p.x, p.y, 0.f);
    }
    if (blockIdx.x == gridDim.x - 1) {
        // W2[k][c] (k*128+c) -> w2bfT[c*128+k] bf16
        for (int idx = tid; idx < HIDDEN * HIDDEN; idx += 256) {
            int k = idx >> 7, c = idx & 127;
            w2bfT[c * HIDDEN + k] = f2bf(W2[idx]);
        }
    }
    __syncthreads();
    int base = blockIdx.x * EPBA;
    int lim = base + EPBA; if (lim > E) lim = E;
    if (base < lim) {
        int n = lim - base;
        int n4 = ((E & 3) == 0) ? (n >> 2) : 0;
        const int4* d4 = (const int4*)(dst + base);
        for (int i = tid; i < n4; i += 256) {
            int4 d = d4[i];
            atomicAdd(&h[d.x >> SUPSH], 1);
            atomicAdd(&h[d.y >> SUPSH], 1);
            atomicAdd(&h[d.z >> SUPSH], 1);
            atomicAdd(&h[d.w >> SUPSH], 1);
        }
        for (int i = base + (n4 << 2) + tid; i < lim; i += 256)
            atomicAdd(&h[dst[i] >> SUPSH], 1);
    }
    __syncthreads();
    if (tid < 64 && blockIdx.x < NBLK) histA[tid * NBLK + blockIdx.x] = h[tid];
}

// Phase A2: 64 blocks, one per super. Exclusive scan of the contiguous column
// histA[s][0..NBLK) -> absolute slot bases (s*CAPA + prefix); bcurA[s] = total.
__global__ __launch_bounds__(256) void k_scanA(int* __restrict__ histA,
                                               int* __restrict__ bcurA, int NBLK) {
    __shared__ int sums[256];
    int s = blockIdx.x;
    int tid = threadIdx.x;
    int* col = histA + (size_t)s * NBLK;
    int per = (NBLK + 255) >> 8;
    int b0 = tid * per;
    int b1 = b0 + per; if (b1 > NBLK) b1 = NBLK; if (b0 > NBLK) b0 = NBLK;
    int sum = 0;
    for (int b = b0; b < b1; ++b) sum += col[b];
    sums[tid] = sum;
    __syncthreads();
    #pragma unroll
    for (int off = 1; off < 256; off <<= 1) {
        int v = (tid >= off) ? sums[tid - off] : 0;
        __syncthreads();
        sums[tid] += v;
        __syncthreads();
    }
    int run = s * CAPA + ((tid == 0) ? 0 : sums[tid - 1]);
    for (int b = b0; b < b1; ++b) { int t = col[b]; col[b] = run; run += t; }
    if (tid == 255) bcurA[s] = sums[255];   // relative total
}

// Phase A3: place edges at precomputed absolute offsets (no global claim atomics).
// entry = src<<10 | (dst & 1023). Reads bases from transposed histA.
__global__ __launch_bounds__(256) void k_placeA(const int* __restrict__ src,
                                                const int* __restrict__ dst,
                                                const int* __restrict__ histA,
                                                unsigned int* __restrict__ pairsA,
                                                int E, int NBLK) {
    __shared__ int h[64];
    __shared__ int hb[64];
    int tid = threadIdx.x;
    if (tid < 64) { hb[tid] = histA[tid * NBLK + blockIdx.x]; h[tid] = 0; }
    __syncthreads();
    int base = blockIdx.x * EPBA;
    int lim = base + EPBA; if (lim > E) lim = E;
    int n = lim - base;
    int n4 = ((E & 3) == 0) ? (n >> 2) : 0;
    const int4* d4 = (const int4*)(dst + base);
    const int4* s4 = (const int4*)(src + base);
#define PUTA(dd, ss) { int sb = (dd) >> SUPSH; int slot = hb[sb] + atomicAdd(&h[sb], 1); \
        if (slot < (sb + 1) * CAPA) pairsA[slot] = ((unsigned)(ss) << SUPSH) | (unsigned)((dd) & 1023); }
    for (int i = tid; i < n4; i += 256) {
        int4 d = d4[i];
        int4 s = s4[i];
        PUTA(d.x, s.x) PUTA(d.y, s.y) PUTA(d.z, s.z) PUTA(d.w, s.w)
    }
    for (int i = base + (n4 << 2) + tid; i < lim; i += 256) {
        int dd = dst[i], ss = src[i];
        PUTA(dd, ss)
    }
#undef PUTA
}

// Phase B: per super bucket, KSUB blocks re-scatter its edges into 64 fine buckets
// of 16 nodes. fine entry = src<<4 | (dst & 15). bcurF relative (memset 0).
__global__ __launch_bounds__(SThrB) void k_scatB(const int* __restrict__ bcurA,
                                                 const unsigned int* __restrict__ pairsA,
                                                 int* __restrict__ bcurF,
                                                 unsigned int* __restrict__ pairsF,
                                                 int NB) {
    __shared__ int h[64];
    __shared__ int hb[64];
    int tid = threadIdx.x;
    int s = blockIdx.x / KSUB;
    int k = blockIdx.x % KSUB;
    int base0 = s * CAPA;
    int ec = bcurA[s]; if (ec > CAPA) ec = CAPA;
    int slice = (((ec + KSUB - 1) / KSUB) + 3) & ~3;   // 4-aligned
    int lo = base0 + k * slice;
    int e1 = base0 + ec;
    int hi = lo + slice; if (hi > e1) hi = e1;
    int n = hi - lo; if (n < 0) n = 0;
    int n4 = n >> 2;                                    // lo is 4-aligned
    const uint4* p4 = (const uint4*)(pairsA + lo);
    if (tid < 64) h[tid] = 0;
    __syncthreads();
    for (int i = tid; i < n4; i += SThrB) {
        uint4 e = p4[i];
        atomicAdd(&h[(e.x >> BSH) & 63u], 1);
        atomicAdd(&h[(e.y >> BSH) & 63u], 1);
        atomicAdd(&h[(e.z >> BSH) & 63u], 1);
        atomicAdd(&h[(e.w >> BSH) & 63u], 1);
    }
    for (int i = lo + (n4 << 2) + tid; i < hi; i += SThrB)
        atomicAdd(&h[(pairsA[i] >> BSH) & 63u], 1);
    __syncthreads();
    if (tid < 64) {
        int c = h[tid];
        int fb = s * 64 + tid;
        hb[tid] = (c && fb < NB) ? atomicAdd(&bcurF[fb], c) : 0;
        h[tid] = 0;
    }
    __syncthreads();
#define PUTB(ee) { int fbl = (int)(((ee) >> BSH) & 63u); int fb = s * 64 + fbl; \
        int loc = hb[fbl] + atomicAdd(&h[fbl], 1); \
        if (fb < NB && loc < CAPF) pairsF[(size_t)fb * CAPF + loc] = (((ee) >> SUPSH) << BSH) | ((ee) & 15u); }
    for (int i = tid; i < n4; i += SThrB) {
        uint4 e = p4[i];
        PUTB(e.x) PUTB(e.y) PUTB(e.z) PUTB(e.w)
    }
    for (int i = lo + (n4 << 2) + tid; i < hi; i += SThrB) {
        unsigned int e = pairsA[i];
        PUTB(e)
    }
#undef PUTB
}

// One block per fine bucket of 16 nodes, single 768-edge chunk. LDS counting-sort;
// place pass packs source features (pjx,pjy via cvt_pk + f32 a) from one xpos[j]
// load; compute pass: per-node effective bias, one b64 broadcast per edge.
// FUSED epilogue: acc -> LDS -> MFMA A-frags; B-frags from L2-hot w2bfT;
// out = acc @ W2 + deg*b2 written directly (no agg roundtrip, no k_w2).
__global__ __launch_bounds__(256) void k_main(const float4* __restrict__ xpos,
                                              const float* __restrict__ W1,
                                              const float* __restrict__ b1,
                                              const unsigned short* __restrict__ w2bfT,
                                              const float* __restrict__ b2,
                                              const int* __restrict__ bcurF,
                                              const unsigned int* __restrict__ pairs,
                                              float* __restrict__ out, int N) {
    __shared__ __align__(16) uint2 f_s[CAPF];       // 6 KiB
    __shared__ __align__(16) float accLds[BNODES][ALDS];  // 8.25 KiB
    __shared__ float degS[BNODES];
    __shared__ int cnt[BNODES];
    __shared__ int offn[BNODES + 1];
    __shared__ int cur[BNODES];

    int tid = threadIdx.x, lane = tid & 63, w = tid >> 6;
    int b = blockIdx.x;
    int n0 = b * BNODES;
    int e0 = b * CAPF;
    int ec = bcurF[b]; if (ec > CAPF) ec = CAPF;

    int c0 = 2 * lane;
    v2f w10 = { W1[c0],              W1[c0 + 1] };
    v2f w11 = { W1[HIDDEN + c0],     W1[HIDDEN + c0 + 1] };
    v2f w12 = { W1[2 * HIDDEN + c0], W1[2 * HIDDEN + c0 + 1] };
    v2f b1v = { b1[c0], b1[c0 + 1] };
    const v2f zero = { 0.f, 0.f };

    if (tid < BNODES) cnt[tid] = 0;
    __syncthreads();
    // register-cache entries (768/256 = 3 per thread) + count pass
    unsigned int rr0 = 0, rr1 = 0, rr2 = 0;
    if (tid + 0 * 256 < ec) rr0 = pairs[e0 + tid + 0 * 256];
    if (tid + 1 * 256 < ec) rr1 = pairs[e0 + tid + 1 * 256];
    if (tid + 2 * 256 < ec) rr2 = pairs[e0 + tid + 2 * 256];
    if (tid + 0 * 256 < ec) atomicAdd(&cnt[rr0 & 15u], 1);
    if (tid + 1 * 256 < ec) atomicAdd(&cnt[rr1 & 15u], 1);
    if (tid + 2 * 256 < ec) atomicAdd(&cnt[rr2 & 15u], 1);
    __syncthreads();
    if (tid < BNODES) {
        int v = cnt[tid];
        int sc = v;
        #pragma unroll
        for (int d = 1; d < BNODES; d <<= 1) {
            int u = __shfl_up(sc, d);
            if (lane >= d) sc += u;
        }
        offn[tid + 1] = sc;
        if (tid == 0) offn[0] = 0;
        cur[tid] = sc - v;  // exclusive
    }
    __syncthreads();
    // place pass: one xpos[j] load, cvt_pk pack (pjx,pjy), raw f32 a, b64 write
    #pragma unroll
    for (int q = 0; q < 3; ++q) {
        unsigned int r = q == 0 ? rr0 : q == 1 ? rr1 : rr2;
        if (tid + q * 256 < ec) {
            int j = (int)(r >> BSH);
            int local = (int)(r & 15u);
            float4 f = xpos[j];
            unsigned pk = cvt_pk_bf16(f.y, f.z);
            int p = atomicAdd(&cur[local], 1);
            f_s[p] = make_uint2(pk, __float_as_uint(f.x));
        }
    }
    __syncthreads();
    // compute pass: per-node effective bias; one b64 broadcast per edge
    #pragma unroll
    for (int s = 0; s < 4; ++s) {
        int l = w * 4 + s;
        int node = n0 + l;
        int sb = offn[l], se = offn[l + 1];
        float4 pi = (node < N) ? xpos[node] : make_float4(0.f, 0.f, 0.f, 0.f);
        v2f t2 = pi.z * w12;
        t2 = pi.y * w11 + t2;
        v2f bb = b1v - t2;
        v2f A = zero;
        #pragma unroll 4
        for (int tt = sb; tt < se; ++tt) {
            uint2 r = f_s[tt];
            float px = __uint_as_float(r.x << 16);
            float py = __uint_as_float(r.x & 0xffff0000u);
            float a  = __uint_as_float(r.y);
            v2f h = a * w10 + bb;
            h = px * w11 + h;
            h = py * w12 + h;
            h = __builtin_elementwise_max(h, zero);
            A += h;
        }
        // stage acc into LDS for MFMA A-frag relayout
        ((v2f*)&accLds[l][0])[lane] = A;
        if (lane == 0) degS[l] = (float)(se - sb);
    }
    __syncthreads();

    // ---- fused @W2 MFMA epilogue (layouts identical to the verified k_w2) ----
    int m = lane & 15;
    int koff = (lane >> 4) * 8;
    bf16x8 afr[4];
    #pragma unroll
    for (int k0 = 0; k0 < 4; ++k0) {
        const float* p = &accLds[m][k0 * 32 + koff];
        float4 fa = *(const float4*)p;
        float4 fb = *(const float4*)(p + 4);
        union { uint4 u; bf16x8 v; } cv;
        cv.u.x = cvt_pk_bf16(fa.x, fa.y);
        cv.u.y = cvt_pk_bf16(fa.z, fa.w);
        cv.u.z = cvt_pk_bf16(fb.x, fb.y);
        cv.u.w = cvt_pk_bf16(fb.z, fb.w);
        afr[k0] = cv.v;
    }

    f32x4 macc[8];
    #pragma unroll
    for (int ct = 0; ct < 8; ++ct) macc[ct] = (f32x4){0.f, 0.f, 0.f, 0.f};

    #pragma unroll
    for (int ct = 0; ct < 8; ++ct) {
        int col = ct * 16 + m;
        #pragma unroll
        for (int k0 = 0; k0 < 4; ++k0) {
            bf16x8 bfrag = *(const bf16x8*)&w2bfT[col * HIDDEN + k0 * 32 + koff];
            macc[ct] = __builtin_amdgcn_mfma_f32_16x16x32_bf16(afr[k0], bfrag, macc[ct], 0, 0, 0);
        }
    }

    int mbase = (lane >> 4) * 4;
    float dg[4];
    #pragma unroll
    for (int i = 0; i < 4; ++i) dg[i] = degS[mbase + i];

    #pragma unroll
    for (int ct = 0; ct < 8; ++ct) {
        int col = ct * 16 + m;
        float b2c = b2[col];
        #pragma unroll
        for (int i = 0; i < 4; ++i) {
            int node = n0 + mbase + i;
            if (node < N) out[(size_t)node * HIDDEN + col] = macc[ct][i] + dg[i] * b2c;
        }
    }
}

extern "C" void kernel_launch(void* const* d_in, const int* in_sizes, int n_in,
                              void* d_out, int out_size, void* d_ws, size_t ws_size,
                              hipStream_t stream) {
    const float* x   = (const float*)d_in[0];
    const float* pos = (const float*)d_in[1];
    const float* W1  = (const float*)d_in[2];
    const float* b1  = (const float*)d_in[3];
    const float* W2  = (const float*)d_in[4];
    const float* b2  = (const float*)d_in[5];
    const int*   ei  = (const int*)d_in[6];

    int N = in_sizes[0];        // x is [N,1]
    int E = in_sizes[6] / 2;    // edge_index is [2,E]
    const int* src = ei;
    const int* dst = ei + E;
    float* out = (float*)d_out;

    int NB   = (N + BNODES - 1) / BNODES;          // fine buckets (16 nodes)
    int NSUP = (N + 1023) >> SUPSH;                // super buckets
    int NBLK = (E + EPBA - 1) / EPBA;              // phase-A blocks

    // ws: bcurA[64] | bcurF[NB] | histA[64*NBLK] | w2bfT[16K u16] | xpos | pairsA | pairsF
    int* bcurA = (int*)d_ws;
    int* bcurF = bcurA + 64;
    int* histA = bcurF + NB;
    unsigned short* w2bfT = (unsigned short*)(histA + (size_t)64 * NBLK);
    float4* xpos = (float4*)(w2bfT + HIDDEN * HIDDEN);
    unsigned int* pairsA = (unsigned int*)(xpos + ((N + 63) & ~63));
    unsigned int* pairsF = pairsA + (size_t)NSUP * CAPA;

    int nblk_nodes = (N + 63) / 64;
    int gribsA = NBLK > nblk_nodes ? NBLK : nblk_nodes;

    hipMemsetAsync(bcurF, 0, (size_t)NB * sizeof(int), stream);
    k_histA<<<gribsA, 256, 0, stream>>>(dst, x, pos, W2, histA, xpos, w2bfT, E, N, NBLK);
    k_scanA<<<64, 256, 0, stream>>>(histA, bcurA, NBLK);
    k_placeA<<<NBLK, 256, 0, stream>>>(src, dst, histA, pairsA, E, NBLK);
    k_scatB<<<NSUP * KSUB, SThrB, 0, stream>>>(bcurA, pairsA, bcurF, pairsF, NB);
    k_main<<<NB, 256, 0, stream>>>(xpos, W1, b1, w2bfT, b2, bcurF, pairsF, out, N);
}

// Round 22
// 92.397 us; speedup vs baseline: 1.4394x; 1.4394x over previous
//
#include <hip/hip_runtime.h>

// PTConv fused: out[i] = (sum_{e: dst=i} relu([x_src, pos_s-pos_i] @ W1 + b1)) @ W2 + deg(i)*b2
// Pipeline: phase-A hist(transposed)->parallel scan(64 blocks)->place (claim-free)
// into 49 super-buckets; phase-B claim-based re-scatter into 16-node fine buckets;
// k_main 256-thr LDS counting-sort + cvt_pk-packed features + effective-bias
// packed-f32 relu-MLP; MFMA bf16 GEMM for @W2. (R15 configuration - best measured.)

#define HIDDEN 128
#define BNODES 16       // nodes per fine bucket
#define BSH 4           // log2(BNODES)
#define SUPSH 10        // super bucket = dst >> 10 (1024 nodes = 64 fine buckets)
#define CAPA 36864      // slots per super bucket (avg 32.7K; +23 sigma)
#define CAPF 768        // slots per fine bucket (avg 512; +11 sigma)
#define EPBA 2048       // edges per phase-A block
#define KSUB 16         // phase-B blocks per super bucket
#define SThrB 512
#define W2LD 136        // padded leading dim for W2^T in LDS (bf16 elems)

typedef float v2f __attribute__((ext_vector_type(2)));
typedef short bf16x8 __attribute__((ext_vector_type(8)));
typedef float f32x4 __attribute__((ext_vector_type(4)));

__device__ __forceinline__ unsigned cvt_pk_bf16(float lo, float hi) {
    unsigned r;
    asm("v_cvt_pk_bf16_f32 %0, %1, %2" : "=v"(r) : "v"(lo), "v"(hi));
    return r;   // [15:0]=bf16(lo), [31:16]=bf16(hi)
}

__device__ __forceinline__ unsigned short f2bf(float f) {
    unsigned int u = __float_as_uint(f);
    u += 0x7fffu + ((u >> 16) & 1u);   // round-to-nearest-even
    return (unsigned short)(u >> 16);
}

// Phase A1: per-block 64-bin histogram, written TRANSPOSED: histA[s*NBLK + b].
// Also packs xpos[n] = {x, px, py, 0}.
__global__ __launch_bounds__(256) void k_histA(const int* __restrict__ dst,
                                               const float* __restrict__ x,
                                               const float* __restrict__ pos,
                                               int* __restrict__ histA,
                                               float4* __restrict__ xpos,
                                               int E, int N, int NBLK) {
    __shared__ int h[64];
    int tid = threadIdx.x;
    if (tid < 64) h[tid] = 0;
    int nb = blockIdx.x * 64 + tid;
    if (tid < 64 && nb < N) {
        float2 p = ((const float2*)pos)[nb];
        xpos[nb] = make_float4(x[nb], p.x, p.y, 0.f);
    }
    __syncthreads();
    int base = blockIdx.x * EPBA;
    int lim = base + EPBA; if (lim > E) lim = E;
    if (base < lim) {
        int n = lim - base;
        int n4 = ((E & 3) == 0) ? (n >> 2) : 0;
        const int4* d4 = (const int4*)(dst + base);
        for (int i = tid; i < n4; i += 256) {
            int4 d = d4[i];
            atomicAdd(&h[d.x >> SUPSH], 1);
            atomicAdd(&h[d.y >> SUPSH], 1);
            atomicAdd(&h[d.z >> SUPSH], 1);
            atomicAdd(&h[d.w >> SUPSH], 1);
        }
        for (int i = base + (n4 << 2) + tid; i < lim; i += 256)
            atomicAdd(&h[dst[i] >> SUPSH], 1);
    }
    __syncthreads();
    if (tid < 64 && blockIdx.x < NBLK) histA[tid * NBLK + blockIdx.x] = h[tid];
}

// Phase A2: 64 blocks, one per super. Exclusive scan of the contiguous column
// histA[s][0..NBLK) -> absolute slot bases (s*CAPA + prefix); bcurA[s] = total.
__global__ __launch_bounds__(256) void k_scanA(int* __restrict__ histA,
                                               int* __restrict__ bcurA, int NBLK) {
    __shared__ int sums[256];
    int s = blockIdx.x;
    int tid = threadIdx.x;
    int* col = histA + (size_t)s * NBLK;
    int per = (NBLK + 255) >> 8;
    int b0 = tid * per;
    int b1 = b0 + per; if (b1 > NBLK) b1 = NBLK; if (b0 > NBLK) b0 = NBLK;
    int sum = 0;
    for (int b = b0; b < b1; ++b) sum += col[b];
    sums[tid] = sum;
    __syncthreads();
    #pragma unroll
    for (int off = 1; off < 256; off <<= 1) {
        int v = (tid >= off) ? sums[tid - off] : 0;
        __syncthreads();
        sums[tid] += v;
        __syncthreads();
    }
    int run = s * CAPA + ((tid == 0) ? 0 : sums[tid - 1]);
    for (int b = b0; b < b1; ++b) { int t = col[b]; col[b] = run; run += t; }
    if (tid == 255) bcurA[s] = sums[255];   // relative total
}

// Phase A3: place edges at precomputed absolute offsets (no global claim atomics).
// entry = src<<10 | (dst & 1023). Reads bases from transposed histA.
__global__ __launch_bounds__(256) void k_placeA(const int* __restrict__ src,
                                                const int* __restrict__ dst,
                                                const int* __restrict__ histA,
                                                unsigned int* __restrict__ pairsA,
                                                int E, int NBLK) {
    __shared__ int h[64];
    __shared__ int hb[64];
    int tid = threadIdx.x;
    if (tid < 64) { hb[tid] = histA[tid * NBLK + blockIdx.x]; h[tid] = 0; }
    __syncthreads();
    int base = blockIdx.x * EPBA;
    int lim = base + EPBA; if (lim > E) lim = E;
    int n = lim - base;
    int n4 = ((E & 3) == 0) ? (n >> 2) : 0;
    const int4* d4 = (const int4*)(dst + base);
    const int4* s4 = (const int4*)(src + base);
#define PUTA(dd, ss) { int sb = (dd) >> SUPSH; int slot = hb[sb] + atomicAdd(&h[sb], 1); \
        if (slot < (sb + 1) * CAPA) pairsA[slot] = ((unsigned)(ss) << SUPSH) | (unsigned)((dd) & 1023); }
    for (int i = tid; i < n4; i += 256) {
        int4 d = d4[i];
        int4 s = s4[i];
        PUTA(d.x, s.x) PUTA(d.y, s.y) PUTA(d.z, s.z) PUTA(d.w, s.w)
    }
    for (int i = base + (n4 << 2) + tid; i < lim; i += 256) {
        int dd = dst[i], ss = src[i];
        PUTA(dd, ss)
    }
#undef PUTA
}

// Phase B: per super bucket, KSUB blocks re-scatter its edges into 64 fine buckets
// of 16 nodes. fine entry = src<<4 | (dst & 15). bcurF relative (memset 0).
__global__ __launch_bounds__(SThrB) void k_scatB(const int* __restrict__ bcurA,
                                                 const unsigned int* __restrict__ pairsA,
                                                 int* __restrict__ bcurF,
                                                 unsigned int* __restrict__ pairsF,
                                                 int NB) {
    __shared__ int h[64];
    __shared__ int hb[64];
    int tid = threadIdx.x;
    int s = blockIdx.x / KSUB;
    int k = blockIdx.x % KSUB;
    int base0 = s * CAPA;
    int ec = bcurA[s]; if (ec > CAPA) ec = CAPA;
    int slice = (((ec + KSUB - 1) / KSUB) + 3) & ~3;   // 4-aligned
    int lo = base0 + k * slice;
    int e1 = base0 + ec;
    int hi = lo + slice; if (hi > e1) hi = e1;
    int n = hi - lo; if (n < 0) n = 0;
    int n4 = n >> 2;                                    // lo is 4-aligned
    const uint4* p4 = (const uint4*)(pairsA + lo);
    if (tid < 64) h[tid] = 0;
    __syncthreads();
    for (int i = tid; i < n4; i += SThrB) {
        uint4 e = p4[i];
        atomicAdd(&h[(e.x >> BSH) & 63u], 1);
        atomicAdd(&h[(e.y >> BSH) & 63u], 1);
        atomicAdd(&h[(e.z >> BSH) & 63u], 1);
        atomicAdd(&h[(e.w >> BSH) & 63u], 1);
    }
    for (int i = lo + (n4 << 2) + tid; i < hi; i += SThrB)
        atomicAdd(&h[(pairsA[i] >> BSH) & 63u], 1);
    __syncthreads();
    if (tid < 64) {
        int c = h[tid];
        int fb = s * 64 + tid;
        hb[tid] = (c && fb < NB) ? atomicAdd(&bcurF[fb], c) : 0;
        h[tid] = 0;
    }
    __syncthreads();
#define PUTB(ee) { int fbl = (int)(((ee) >> BSH) & 63u); int fb = s * 64 + fbl; \
        int loc = hb[fbl] + atomicAdd(&h[fbl], 1); \
        if (fb < NB && loc < CAPF) pairsF[(size_t)fb * CAPF + loc] = (((ee) >> SUPSH) << BSH) | ((ee) & 15u); }
    for (int i = tid; i < n4; i += SThrB) {
        uint4 e = p4[i];
        PUTB(e.x) PUTB(e.y) PUTB(e.z) PUTB(e.w)
    }
    for (int i = lo + (n4 << 2) + tid; i < hi; i += SThrB) {
        unsigned int e = pairsA[i];
        PUTB(e)
    }
#undef PUTB
}

// One block per fine bucket of 16 nodes, single 768-edge chunk. Counting-sort by
// local node id in LDS; place pass packs source features (pjx,pjy via cvt_pk + f32 a)
// from one xpos[j] load; compute pass uses per-node effective bias
// bb = b1 - pix*w11 - piy*w12, one b64 broadcast per edge, packed-f32 MLP.
__global__ __launch_bounds__(256) void k_main(const float4* __restrict__ xpos,
                                              const float* __restrict__ W1,
                                              const float* __restrict__ b1,
                                              const int* __restrict__ bcurF,
                                              const unsigned int* __restrict__ pairs,
                                              float* __restrict__ agg,
                                              int* __restrict__ deg, int N) {
    __shared__ uint2 f_s[CAPF];          // 6 KiB
    __shared__ int cnt[BNODES];
    __shared__ int offn[BNODES + 1];
    __shared__ int cur[BNODES];

    int tid = threadIdx.x, lane = tid & 63, w = tid >> 6;
    int b = blockIdx.x;
    int n0 = b * BNODES;
    int e0 = b * CAPF;
    int ec = bcurF[b]; if (ec > CAPF) ec = CAPF;

    int c0 = 2 * lane;
    v2f w10 = { W1[c0],              W1[c0 + 1] };
    v2f w11 = { W1[HIDDEN + c0],     W1[HIDDEN + c0 + 1] };
    v2f w12 = { W1[2 * HIDDEN + c0], W1[2 * HIDDEN + c0 + 1] };
    v2f b1v = { b1[c0], b1[c0 + 1] };
    const v2f zero = { 0.f, 0.f };

    if (tid < BNODES) cnt[tid] = 0;
    __syncthreads();
    // register-cache entries (768/256 = 3 per thread) + count pass
    unsigned int rr0 = 0, rr1 = 0, rr2 = 0;
    if (tid + 0 * 256 < ec) rr0 = pairs[e0 + tid + 0 * 256];
    if (tid + 1 * 256 < ec) rr1 = pairs[e0 + tid + 1 * 256];
    if (tid + 2 * 256 < ec) rr2 = pairs[e0 + tid + 2 * 256];
    if (tid + 0 * 256 < ec) atomicAdd(&cnt[rr0 & 15u], 1);
    if (tid + 1 * 256 < ec) atomicAdd(&cnt[rr1 & 15u], 1);
    if (tid + 2 * 256 < ec) atomicAdd(&cnt[rr2 & 15u], 1);
    __syncthreads();
    if (tid < BNODES) {
        int v = cnt[tid];
        int sc = v;
        #pragma unroll
        for (int d = 1; d < BNODES; d <<= 1) {
            int u = __shfl_up(sc, d);
            if (lane >= d) sc += u;
        }
        offn[tid + 1] = sc;
        if (tid == 0) offn[0] = 0;
        cur[tid] = sc - v;  // exclusive
    }
    __syncthreads();
    // place pass: one xpos[j] load, cvt_pk pack (pjx,pjy), raw f32 a, b64 write
    #pragma unroll
    for (int q = 0; q < 3; ++q) {
        unsigned int r = q == 0 ? rr0 : q == 1 ? rr1 : rr2;
        if (tid + q * 256 < ec) {
            int j = (int)(r >> BSH);
            int local = (int)(r & 15u);
            float4 f = xpos[j];
            unsigned pk = cvt_pk_bf16(f.y, f.z);
            int p = atomicAdd(&cur[local], 1);
            f_s[p] = make_uint2(pk, __float_as_uint(f.x));
        }
    }
    __syncthreads();
    // compute pass: per-node effective bias; one b64 broadcast per edge
    v2f acc[4];
    int dga[4];
    #pragma unroll
    for (int s = 0; s < 4; ++s) {
        int l = w * 4 + s;
        int node = n0 + l;
        int sb = offn[l], se = offn[l + 1];
        dga[s] = se - sb;
        float4 pi = (node < N) ? xpos[node] : make_float4(0.f, 0.f, 0.f, 0.f);
        v2f t2 = pi.z * w12;
        t2 = pi.y * w11 + t2;
        v2f bb = b1v - t2;
        v2f A = zero;
        #pragma unroll 4
        for (int tt = sb; tt < se; ++tt) {
            uint2 r = f_s[tt];
            float px = __uint_as_float(r.x << 16);
            float py = __uint_as_float(r.x & 0xffff0000u);
            float a  = __uint_as_float(r.y);
            v2f h = a * w10 + bb;
            h = px * w11 + h;
            h = py * w12 + h;
            h = __builtin_elementwise_max(h, zero);
            A += h;
        }
        acc[s] = A;
    }

    #pragma unroll
    for (int s = 0; s < 4; ++s) {
        int l = w * 4 + s;
        int node = n0 + l;
        if (node < N) {
            ((v2f*)&agg[(size_t)node * HIDDEN])[lane] = acc[s];
            if (lane == 0) deg[node] = dga[s];
        }
    }
}

// MFMA GEMM: out = agg @ W2 + deg*b2, in place on d_out (agg==out, f32).
// Each block: 64 rows (4 waves x 16). W2^T staged bf16 in LDS (pad 136).
__global__ __launch_bounds__(256) void k_w2(float* __restrict__ agg,
                                            const float* __restrict__ W2,
                                            const float* __restrict__ b2,
                                            const int* __restrict__ deg, int N) {
    __shared__ unsigned short w2t[HIDDEN * W2LD];  // 34 KiB, W2^T[c][k]
    int tid = threadIdx.x;
    for (int idx = tid; idx < HIDDEN * HIDDEN; idx += 256) {
        int k = idx >> 7, c = idx & 127;            // idx = k*128 + c
        w2t[c * W2LD + k] = f2bf(W2[idx]);
    }
    __syncthreads();

    int lane = tid & 63, w = tid >> 6;
    int row0 = blockIdx.x * 64 + w * 16;
    if (row0 >= N) return;

    int rA = row0 + (lane & 15);
    int koff = (lane >> 4) * 8;
    bool okA = rA < N;

    bf16x8 a[4];
    #pragma unroll
    for (int k0 = 0; k0 < 4; ++k0) {
        float4 fa = {0.f,0.f,0.f,0.f}, fb = {0.f,0.f,0.f,0.f};
        if (okA) {
            const float4* p = (const float4*)&agg[(size_t)rA * HIDDEN + k0 * 32 + koff];
            fa = p[0]; fb = p[1];
        }
        union { uint4 u; bf16x8 v; } cv;
        cv.u.x = cvt_pk_bf16(fa.x, fa.y);
        cv.u.y = cvt_pk_bf16(fa.z, fa.w);
        cv.u.z = cvt_pk_bf16(fb.x, fb.y);
        cv.u.w = cvt_pk_bf16(fb.z, fb.w);
        a[k0] = cv.v;
    }

    f32x4 acc[8];
    #pragma unroll
    for (int ct = 0; ct < 8; ++ct) acc[ct] = (f32x4){0.f,0.f,0.f,0.f};

    #pragma unroll
    for (int ct = 0; ct < 8; ++ct) {
        int col = ct * 16 + (lane & 15);
        #pragma unroll
        for (int k0 = 0; k0 < 4; ++k0) {
            bf16x8 bfrag = *(const bf16x8*)&w2t[col * W2LD + k0 * 32 + koff];
            acc[ct] = __builtin_amdgcn_mfma_f32_16x16x32_bf16(a[k0], bfrag, acc[ct], 0, 0, 0);
        }
    }

    int mbase = row0 + (lane >> 4) * 4;
    float dg[4];
    #pragma unroll
    for (int i = 0; i < 4; ++i) dg[i] = (mbase + i < N) ? (float)deg[mbase + i] : 0.f;

    #pragma unroll
    for (int ct = 0; ct < 8; ++ct) {
        int col = ct * 16 + (lane & 15);
        float b2c = b2[col];
        #pragma unroll
        for (int i = 0; i < 4; ++i) {
            int r = mbase + i;
            if (r < N) agg[(size_t)r * HIDDEN + col] = acc[ct][i] + dg[i] * b2c;
        }
    }
}

extern "C" void kernel_launch(void* const* d_in, const int* in_sizes, int n_in,
                              void* d_out, int out_size, void* d_ws, size_t ws_size,
                              hipStream_t stream) {
    const float* x   = (const float*)d_in[0];
    const float* pos = (const float*)d_in[1];
    const float* W1  = (const float*)d_in[2];
    const float* b1  = (const float*)d_in[3];
    const float* W2  = (const float*)d_in[4];
    const float* b2  = (const float*)d_in[5];
    const int*   ei  = (const int*)d_in[6];

    int N = in_sizes[0];        // x is [N,1]
    int E = in_sizes[6] / 2;    // edge_index is [2,E]
    const int* src = ei;
    const int* dst = ei + E;
    float* out = (float*)d_out;

    int NB   = (N + BNODES - 1) / BNODES;          // fine buckets (16 nodes)
    int NSUP = (N + 1023) >> SUPSH;                // super buckets
    int NBLK = (E + EPBA - 1) / EPBA;              // phase-A blocks

    // ws: bcurA[64] | bcurF[NB] | deg[N] | histA[64*NBLK] | xpos[N pad] | pairsA | pairsF
    int* bcurA = (int*)d_ws;
    int* bcurF = bcurA + 64;
    int* deg   = bcurF + NB;
    int* histA = deg + N;
    float4* xpos = (float4*)(histA + (size_t)64 * NBLK);
    unsigned int* pairsA = (unsigned int*)(xpos + ((N + 63) & ~63));
    unsigned int* pairsF = pairsA + (size_t)NSUP * CAPA;

    int nblk_nodes = (N + 63) / 64;
    int gribsA = NBLK > nblk_nodes ? NBLK : nblk_nodes;

    hipMemsetAsync(bcurF, 0, (size_t)NB * sizeof(int), stream);
    k_histA<<<gribsA, 256, 0, stream>>>(dst, x, pos, histA, xpos, E, N, NBLK);
    k_scanA<<<64, 256, 0, stream>>>(histA, bcurA, NBLK);
    k_placeA<<<NBLK, 256, 0, stream>>>(src, dst, histA, pairsA, E, NBLK);
    k_scatB<<<NSUP * KSUB, SThrB, 0, stream>>>(bcurA, pairsA, bcurF, pairsF, NB);
    k_main<<<NB, 256, 0, stream>>>(xpos, W1, b1, bcurF, pairsF, out, deg, N);
    k_w2<<<(N + 63) / 64, 256, 0, stream>>>(out, W2, b2, deg, N);
}

// Round 23
// 92.123 us; speedup vs baseline: 1.4436x; 1.0030x over previous
//
#include <hip/hip_runtime.h>

// PTConv fused: out[i] = (sum_{e: dst=i} relu([x_src, pos_s-pos_i] @ W1 + b1)) @ W2 + deg(i)*b2
// Pipeline: phase-A hist(transposed)->parallel scan(64 blocks)->place (claim-free)
// into 49 super-buckets; phase-B claim-based re-scatter (KSUB=24) into 16-node fine
// buckets; k_main 256-thr LDS counting-sort + cvt_pk-packed features + effective-bias
// packed-f32 relu-MLP (unroll 8); MFMA bf16 GEMM for @W2.

#define HIDDEN 128
#define BNODES 16       // nodes per fine bucket
#define BSH 4           // log2(BNODES)
#define SUPSH 10        // super bucket = dst >> 10 (1024 nodes = 64 fine buckets)
#define CAPA 36864      // slots per super bucket (avg 32.7K; +23 sigma)
#define CAPF 768        // slots per fine bucket (avg 512; +11 sigma)
#define EPBA 2048       // edges per phase-A block
#define KSUB 24         // phase-B blocks per super bucket
#define SThrB 512
#define W2LD 136        // padded leading dim for W2^T in LDS (bf16 elems)

typedef float v2f __attribute__((ext_vector_type(2)));
typedef short bf16x8 __attribute__((ext_vector_type(8)));
typedef float f32x4 __attribute__((ext_vector_type(4)));

__device__ __forceinline__ unsigned cvt_pk_bf16(float lo, float hi) {
    unsigned r;
    asm("v_cvt_pk_bf16_f32 %0, %1, %2" : "=v"(r) : "v"(lo), "v"(hi));
    return r;   // [15:0]=bf16(lo), [31:16]=bf16(hi)
}

__device__ __forceinline__ unsigned short f2bf(float f) {
    unsigned int u = __float_as_uint(f);
    u += 0x7fffu + ((u >> 16) & 1u);   // round-to-nearest-even
    return (unsigned short)(u >> 16);
}

// Phase A1: per-block 64-bin histogram, written TRANSPOSED: histA[s*NBLK + b].
// Also packs xpos[n] = {x, px, py, 0}.
__global__ __launch_bounds__(256) void k_histA(const int* __restrict__ dst,
                                               const float* __restrict__ x,
                                               const float* __restrict__ pos,
                                               int* __restrict__ histA,
                                               float4* __restrict__ xpos,
                                               int E, int N, int NBLK) {
    __shared__ int h[64];
    int tid = threadIdx.x;
    if (tid < 64) h[tid] = 0;
    int nb = blockIdx.x * 64 + tid;
    if (tid < 64 && nb < N) {
        float2 p = ((const float2*)pos)[nb];
        xpos[nb] = make_float4(x[nb], p.x, p.y, 0.f);
    }
    __syncthreads();
    int base = blockIdx.x * EPBA;
    int lim = base + EPBA; if (lim > E) lim = E;
    if (base < lim) {
        int n = lim - base;
        int n4 = ((E & 3) == 0) ? (n >> 2) : 0;
        const int4* d4 = (const int4*)(dst + base);
        for (int i = tid; i < n4; i += 256) {
            int4 d = d4[i];
            atomicAdd(&h[d.x >> SUPSH], 1);
            atomicAdd(&h[d.y >> SUPSH], 1);
            atomicAdd(&h[d.z >> SUPSH], 1);
            atomicAdd(&h[d.w >> SUPSH], 1);
        }
        for (int i = base + (n4 << 2) + tid; i < lim; i += 256)
            atomicAdd(&h[dst[i] >> SUPSH], 1);
    }
    __syncthreads();
    if (tid < 64 && blockIdx.x < NBLK) histA[tid * NBLK + blockIdx.x] = h[tid];
}

// Phase A2: 64 blocks, one per super. Exclusive scan of the contiguous column
// histA[s][0..NBLK) -> absolute slot bases (s*CAPA + prefix); bcurA[s] = total.
__global__ __launch_bounds__(256) void k_scanA(int* __restrict__ histA,
                                               int* __restrict__ bcurA, int NBLK) {
    __shared__ int sums[256];
    int s = blockIdx.x;
    int tid = threadIdx.x;
    int* col = histA + (size_t)s * NBLK;
    int per = (NBLK + 255) >> 8;
    int b0 = tid * per;
    int b1 = b0 + per; if (b1 > NBLK) b1 = NBLK; if (b0 > NBLK) b0 = NBLK;
    int sum = 0;
    for (int b = b0; b < b1; ++b) sum += col[b];
    sums[tid] = sum;
    __syncthreads();
    #pragma unroll
    for (int off = 1; off < 256; off <<= 1) {
        int v = (tid >= off) ? sums[tid - off] : 0;
        __syncthreads();
        sums[tid] += v;
        __syncthreads();
    }
    int run = s * CAPA + ((tid == 0) ? 0 : sums[tid - 1]);
    for (int b = b0; b < b1; ++b) { int t = col[b]; col[b] = run; run += t; }
    if (tid == 255) bcurA[s] = sums[255];   // relative total
}

// Phase A3: place edges at precomputed absolute offsets (no global claim atomics).
// entry = src<<10 | (dst & 1023). Reads bases from transposed histA.
__global__ __launch_bounds__(256) void k_placeA(const int* __restrict__ src,
                                                const int* __restrict__ dst,
                                                const int* __restrict__ histA,
                                                unsigned int* __restrict__ pairsA,
                                                int E, int NBLK) {
    __shared__ int h[64];
    __shared__ int hb[64];
    int tid = threadIdx.x;
    if (tid < 64) { hb[tid] = histA[tid * NBLK + blockIdx.x]; h[tid] = 0; }
    __syncthreads();
    int base = blockIdx.x * EPBA;
    int lim = base + EPBA; if (lim > E) lim = E;
    int n = lim - base;
    int n4 = ((E & 3) == 0) ? (n >> 2) : 0;
    const int4* d4 = (const int4*)(dst + base);
    const int4* s4 = (const int4*)(src + base);
#define PUTA(dd, ss) { int sb = (dd) >> SUPSH; int slot = hb[sb] + atomicAdd(&h[sb], 1); \
        if (slot < (sb + 1) * CAPA) pairsA[slot] = ((unsigned)(ss) << SUPSH) | (unsigned)((dd) & 1023); }
    for (int i = tid; i < n4; i += 256) {
        int4 d = d4[i];
        int4 s = s4[i];
        PUTA(d.x, s.x) PUTA(d.y, s.y) PUTA(d.z, s.z) PUTA(d.w, s.w)
    }
    for (int i = base + (n4 << 2) + tid; i < lim; i += 256) {
        int dd = dst[i], ss = src[i];
        PUTA(dd, ss)
    }
#undef PUTA
}

// Phase B: per super bucket, KSUB blocks re-scatter its edges into 64 fine buckets
// of 16 nodes. fine entry = src<<4 | (dst & 15). bcurF relative (memset 0).
__global__ __launch_bounds__(SThrB) void k_scatB(const int* __restrict__ bcurA,
                                                 const unsigned int* __restrict__ pairsA,
                                                 int* __restrict__ bcurF,
                                                 unsigned int* __restrict__ pairsF,
                                                 int NB) {
    __shared__ int h[64];
    __shared__ int hb[64];
    int tid = threadIdx.x;
    int s = blockIdx.x / KSUB;
    int k = blockIdx.x % KSUB;
    int base0 = s * CAPA;
    int ec = bcurA[s]; if (ec > CAPA) ec = CAPA;
    int slice = (((ec + KSUB - 1) / KSUB) + 3) & ~3;   // 4-aligned
    int lo = base0 + k * slice;
    int e1 = base0 + ec;
    int hi = lo + slice; if (hi > e1) hi = e1;
    int n = hi - lo; if (n < 0) n = 0;
    int n4 = n >> 2;                                    // lo is 4-aligned
    const uint4* p4 = (const uint4*)(pairsA + lo);
    if (tid < 64) h[tid] = 0;
    __syncthreads();
    for (int i = tid; i < n4; i += SThrB) {
        uint4 e = p4[i];
        atomicAdd(&h[(e.x >> BSH) & 63u], 1);
        atomicAdd(&h[(e.y >> BSH) & 63u], 1);
        atomicAdd(&h[(e.z >> BSH) & 63u], 1);
        atomicAdd(&h[(e.w >> BSH) & 63u], 1);
    }
    for (int i = lo + (n4 << 2) + tid; i < hi; i += SThrB)
        atomicAdd(&h[(pairsA[i] >> BSH) & 63u], 1);
    __syncthreads();
    if (tid < 64) {
        int c = h[tid];
        int fb = s * 64 + tid;
        hb[tid] = (c && fb < NB) ? atomicAdd(&bcurF[fb], c) : 0;
        h[tid] = 0;
    }
    __syncthreads();
#define PUTB(ee) { int fbl = (int)(((ee) >> BSH) & 63u); int fb = s * 64 + fbl; \
        int loc = hb[fbl] + atomicAdd(&h[fbl], 1); \
        if (fb < NB && loc < CAPF) pairsF[(size_t)fb * CAPF + loc] = (((ee) >> SUPSH) << BSH) | ((ee) & 15u); }
    for (int i = tid; i < n4; i += SThrB) {
        uint4 e = p4[i];
        PUTB(e.x) PUTB(e.y) PUTB(e.z) PUTB(e.w)
    }
    for (int i = lo + (n4 << 2) + tid; i < hi; i += SThrB) {
        unsigned int e = pairsA[i];
        PUTB(e)
    }
#undef PUTB
}

// One block per fine bucket of 16 nodes, single 768-edge chunk. Counting-sort by
// local node id in LDS; place pass packs source features (pjx,pjy via cvt_pk + f32 a)
// from one xpos[j] load; compute pass uses per-node effective bias
// bb = b1 - pix*w11 - piy*w12, one b64 broadcast per edge, packed-f32 MLP.
__global__ __launch_bounds__(256) void k_main(const float4* __restrict__ xpos,
                                              const float* __restrict__ W1,
                                              const float* __restrict__ b1,
                                              const int* __restrict__ bcurF,
                                              const unsigned int* __restrict__ pairs,
                                              float* __restrict__ agg,
                                              int* __restrict__ deg, int N) {
    __shared__ uint2 f_s[CAPF];          // 6 KiB
    __shared__ int cnt[BNODES];
    __shared__ int offn[BNODES + 1];
    __shared__ int cur[BNODES];

    int tid = threadIdx.x, lane = tid & 63, w = tid >> 6;
    int b = blockIdx.x;
    int n0 = b * BNODES;
    int e0 = b * CAPF;
    int ec = bcurF[b]; if (ec > CAPF) ec = CAPF;

    int c0 = 2 * lane;
    v2f w10 = { W1[c0],              W1[c0 + 1] };
    v2f w11 = { W1[HIDDEN + c0],     W1[HIDDEN + c0 + 1] };
    v2f w12 = { W1[2 * HIDDEN + c0], W1[2 * HIDDEN + c0 + 1] };
    v2f b1v = { b1[c0], b1[c0 + 1] };
    const v2f zero = { 0.f, 0.f };

    if (tid < BNODES) cnt[tid] = 0;
    __syncthreads();
    // register-cache entries (768/256 = 3 per thread) + count pass
    unsigned int rr0 = 0, rr1 = 0, rr2 = 0;
    if (tid + 0 * 256 < ec) rr0 = pairs[e0 + tid + 0 * 256];
    if (tid + 1 * 256 < ec) rr1 = pairs[e0 + tid + 1 * 256];
    if (tid + 2 * 256 < ec) rr2 = pairs[e0 + tid + 2 * 256];
    if (tid + 0 * 256 < ec) atomicAdd(&cnt[rr0 & 15u], 1);
    if (tid + 1 * 256 < ec) atomicAdd(&cnt[rr1 & 15u], 1);
    if (tid + 2 * 256 < ec) atomicAdd(&cnt[rr2 & 15u], 1);
    __syncthreads();
    if (tid < BNODES) {
        int v = cnt[tid];
        int sc = v;
        #pragma unroll
        for (int d = 1; d < BNODES; d <<= 1) {
            int u = __shfl_up(sc, d);
            if (lane >= d) sc += u;
        }
        offn[tid + 1] = sc;
        if (tid == 0) offn[0] = 0;
        cur[tid] = sc - v;  // exclusive
    }
    __syncthreads();
    // place pass: one xpos[j] load, cvt_pk pack (pjx,pjy), raw f32 a, b64 write
    #pragma unroll
    for (int q = 0; q < 3; ++q) {
        unsigned int r = q == 0 ? rr0 : q == 1 ? rr1 : rr2;
        if (tid + q * 256 < ec) {
            int j = (int)(r >> BSH);
            int local = (int)(r & 15u);
            float4 f = xpos[j];
            unsigned pk = cvt_pk_bf16(f.y, f.z);
            int p = atomicAdd(&cur[local], 1);
            f_s[p] = make_uint2(pk, __float_as_uint(f.x));
        }
    }
    __syncthreads();
    // compute pass: per-node effective bias; one b64 broadcast per edge
    v2f acc[4];
    int dga[4];
    #pragma unroll
    for (int s = 0; s < 4; ++s) {
        int l = w * 4 + s;
        int node = n0 + l;
        int sb = offn[l], se = offn[l + 1];
        dga[s] = se - sb;
        float4 pi = (node < N) ? xpos[node] : make_float4(0.f, 0.f, 0.f, 0.f);
        v2f t2 = pi.z * w12;
        t2 = pi.y * w11 + t2;
        v2f bb = b1v - t2;
        v2f A = zero;
        #pragma unroll 8
        for (int tt = sb; tt < se; ++tt) {
            uint2 r = f_s[tt];
            float px = __uint_as_float(r.x << 16);
            float py = __uint_as_float(r.x & 0xffff0000u);
            float a  = __uint_as_float(r.y);
            v2f h = a * w10 + bb;
            h = px * w11 + h;
            h = py * w12 + h;
            h = __builtin_elementwise_max(h, zero);
            A += h;
        }
        acc[s] = A;
    }

    #pragma unroll
    for (int s = 0; s < 4; ++s) {
        int l = w * 4 + s;
        int node = n0 + l;
        if (node < N) {
            ((v2f*)&agg[(size_t)node * HIDDEN])[lane] = acc[s];
            if (lane == 0) deg[node] = dga[s];
        }
    }
}

// MFMA GEMM: out = agg @ W2 + deg*b2, in place on d_out (agg==out, f32).
// Each block: 64 rows (4 waves x 16). W2^T staged bf16 in LDS (pad 136).
__global__ __launch_bounds__(256) void k_w2(float* __restrict__ agg,
                                            const float* __restrict__ W2,
                                            const float* __restrict__ b2,
                                            const int* __restrict__ deg, int N) {
    __shared__ unsigned short w2t[HIDDEN * W2LD];  // 34 KiB, W2^T[c][k]
    int tid = threadIdx.x;
    for (int idx = tid; idx < HIDDEN * HIDDEN; idx += 256) {
        int k = idx >> 7, c = idx & 127;            // idx = k*128 + c
        w2t[c * W2LD + k] = f2bf(W2[idx]);
    }
    __syncthreads();

    int lane = tid & 63, w = tid >> 6;
    int row0 = blockIdx.x * 64 + w * 16;
    if (row0 >= N) return;

    int rA = row0 + (lane & 15);
    int koff = (lane >> 4) * 8;
    bool okA = rA < N;

    bf16x8 a[4];
    #pragma unroll
    for (int k0 = 0; k0 < 4; ++k0) {
        float4 fa = {0.f,0.f,0.f,0.f}, fb = {0.f,0.f,0.f,0.f};
        if (okA) {
            const float4* p = (const float4*)&agg[(size_t)rA * HIDDEN + k0 * 32 + koff];
            fa = p[0]; fb = p[1];
        }
        union { uint4 u; bf16x8 v; } cv;
        cv.u.x = cvt_pk_bf16(fa.x, fa.y);
        cv.u.y = cvt_pk_bf16(fa.z, fa.w);
        cv.u.z = cvt_pk_bf16(fb.x, fb.y);
        cv.u.w = cvt_pk_bf16(fb.z, fb.w);
        a[k0] = cv.v;
    }

    f32x4 acc[8];
    #pragma unroll
    for (int ct = 0; ct < 8; ++ct) acc[ct] = (f32x4){0.f,0.f,0.f,0.f};

    #pragma unroll
    for (int ct = 0; ct < 8; ++ct) {
        int col = ct * 16 + (lane & 15);
        #pragma unroll
        for (int k0 = 0; k0 < 4; ++k0) {
            bf16x8 bfrag = *(const bf16x8*)&w2t[col * W2LD + k0 * 32 + koff];
            acc[ct] = __builtin_amdgcn_mfma_f32_16x16x32_bf16(a[k0], bfrag, acc[ct], 0, 0, 0);
        }
    }

    int mbase = row0 + (lane >> 4) * 4;
    float dg[4];
    #pragma unroll
    for (int i = 0; i < 4; ++i) dg[i] = (mbase + i < N) ? (float)deg[mbase + i] : 0.f;

    #pragma unroll
    for (int ct = 0; ct < 8; ++ct) {
        int col = ct * 16 + (lane & 15);
        float b2c = b2[col];
        #pragma unroll
        for (int i = 0; i < 4; ++i) {
            int r = mbase + i;
            if (r < N) agg[(size_t)r * HIDDEN + col] = acc[ct][i] + dg[i] * b2c;
        }
    }
}

extern "C" void kernel_launch(void* const* d_in, const int* in_sizes, int n_in,
                              void* d_out, int out_size, void* d_ws, size_t ws_size,
                              hipStream_t stream) {
    const float* x   = (const float*)d_in[0];
    const float* pos = (const float*)d_in[1];
    const float* W1  = (const float*)d_in[2];
    const float* b1  = (const float*)d_in[3];
    const float* W2  = (const float*)d_in[4];
    const float* b2  = (const float*)d_in[5];
    const int*   ei  = (const int*)d_in[6];

    int N = in_sizes[0];        // x is [N,1]
    int E = in_sizes[6] / 2;    // edge_index is [2,E]
    const int* src = ei;
    const int* dst = ei + E;
    float* out = (float*)d_out;

    int NB   = (N + BNODES - 1) / BNODES;          // fine buckets (16 nodes)
    int NSUP = (N + 1023) >> SUPSH;                // super buckets
    int NBLK = (E + EPBA - 1) / EPBA;              // phase-A blocks

    // ws: bcurA[64] | bcurF[NB] | deg[N] | histA[64*NBLK] | xpos[N pad] | pairsA | pairsF
    int* bcurA = (int*)d_ws;
    int* bcurF = bcurA + 64;
    int* deg   = bcurF + NB;
    int* histA = deg + N;
    float4* xpos = (float4*)(histA + (size_t)64 * NBLK);
    unsigned int* pairsA = (unsigned int*)(xpos + ((N + 63) & ~63));
    unsigned int* pairsF = pairsA + (size_t)NSUP * CAPA;

    int nblk_nodes = (N + 63) / 64;
    int gribsA = NBLK > nblk_nodes ? NBLK : nblk_nodes;

    hipMemsetAsync(bcurF, 0, (size_t)NB * sizeof(int), stream);
    k_histA<<<gribsA, 256, 0, stream>>>(dst, x, pos, histA, xpos, E, N, NBLK);
    k_scanA<<<64, 256, 0, stream>>>(histA, bcurA, NBLK);
    k_placeA<<<NBLK, 256, 0, stream>>>(src, dst, histA, pairsA, E, NBLK);
    k_scatB<<<NSUP * KSUB, SThrB, 0, stream>>>(bcurA, pairsA, bcurF, pairsF, NB);
    k_main<<<NB, 256, 0, stream>>>(xpos, W1, b1, bcurF, pairsF, out, deg, N);
    k_w2<<<(N + 63) / 64, 256, 0, stream>>>(out, W2, b2, deg, N);
}